// Round 11
// baseline (264.109 us; speedup 1.0000x reference)
//
#include <hip/hip_runtime.h>
#include <hip/hip_cooperative_groups.h>

namespace cg = cooperative_groups;

// GCN layer: out = A_norm @ (h @ W^T + b), A_norm = D^-1/2 (A + I) D^-1/2
// Inputs: h [N,128] f32, W [128,128] f32, b [128] f32, edges [2,E] int32
// Output: [N,128] f32
//
// R11: CSR-build chain (memset+count+scan1+scan3, 4 launches) fused into
// ONE cooperative kernel with grid.sync() phases. k_fill stays fused with
// the MFMA linear (scatter latency hides under GEMM); k_agg unchanged
// (half-wave/node, ushort4 bf16 gathers — at its L3-gather byte floor).

#define IN_DIM 128
#define OUT_DIM 128

typedef short bf16x8 __attribute__((ext_vector_type(8)));
typedef float f32x4 __attribute__((ext_vector_type(4)));

__device__ __forceinline__ unsigned short f2bf(float f) {
    unsigned u = __float_as_uint(f);
    u += 0x7fffu + ((u >> 16) & 1u);  // round-nearest-even
    return (unsigned short)(u >> 16);
}
__device__ __forceinline__ float bf2f(unsigned short s) {
    return __uint_as_float(((unsigned)s) << 16);
}

// Cooperative build: zero cnt -> count/rank -> chunk scan -> base+rs.
// Grid: 256 blocks x 1024 thr (16 waves/CU, co-resident). nb <= 64 chunks.
__global__ __launch_bounds__(1024) void k_build(const int* __restrict__ dst,
                                                int* __restrict__ cnt,
                                                int* __restrict__ rank,
                                                int* __restrict__ off,
                                                int* __restrict__ bsum,
                                                float* __restrict__ rs,
                                                int n, int E, int nb) {
    cg::grid_group grid = cg::this_grid();
    __shared__ int wsum[16];
    __shared__ int sbase;
    const int tid = threadIdx.x;
    const int gid = blockIdx.x * 1024 + tid;
    const int gsz = gridDim.x * 1024;

    // Phase 0: zero degree counters (ws is poisoned 0xAA each launch)
    for (int i = gid; i < n; i += gsz) cnt[i] = 0;
    grid.sync();

    // Phase 1: count degrees, record per-edge arrival rank
    for (int e = gid; e < E; e += gsz) rank[e] = atomicAdd(&cnt[dst[e]], 1);
    grid.sync();

    // Phase 2: per-chunk exclusive scan (chunk c = block c, c < nb)
    if ((int)blockIdx.x < nb) {
        const int lane = tid & 63;
        const int wv = tid >> 6;
        int i = blockIdx.x * 1024 + tid;
        int v = (i < n) ? cnt[i] : 0;
        int x = v;
#pragma unroll
        for (int d = 1; d < 64; d <<= 1) {
            int t = __shfl_up(x, d, 64);
            if (lane >= d) x += t;
        }
        if (lane == 63) wsum[wv] = x;
        __syncthreads();
        if (wv == 0) {
            int y = (lane < 16) ? wsum[lane] : 0;
#pragma unroll
            for (int d = 1; d < 16; d <<= 1) {
                int t = __shfl_up(y, d, 64);
                if (lane >= d) y += t;
            }
            if (lane < 16) wsum[lane] = y;
        }
        __syncthreads();
        int waveoff = (wv == 0) ? 0 : wsum[wv - 1];
        if (i < n) off[i] = waveoff + x - v;
        if (tid == 0) bsum[blockIdx.x] = wsum[15];
    }
    grid.sync();

    // Phase 3: add chunk base (each block's wave 0 scans bsum); emit rs.
    if ((int)blockIdx.x < nb) {
        if (tid < 64) {
            int v = (tid < nb) ? bsum[tid] : 0;
            int x = v;
#pragma unroll
            for (int d = 1; d < 64; d <<= 1) {
                int t = __shfl_up(x, d, 64);
                if (tid >= d) x += t;
            }
            if (tid == (int)blockIdx.x) sbase = x - v;         // exclusive base
            if (blockIdx.x == 0 && tid == nb - 1) off[n] = x;  // grand total
        }
        __syncthreads();
        int i = blockIdx.x * 1024 + tid;
        if (i < n) {
            off[i] = off[i] + sbase;
            rs[i] = rsqrtf((float)(cnt[i] + 1));
        }
    }
}

// Fused: blocks [0,nlin) compute hs = (h@W^T+b)*rs via MFMA;
// blocks [nlin, nlin+NFB) do the atomic-free CSR fill (grid-stride chunks).
#define NFB 1024
__global__ __launch_bounds__(256) void k_fill_linear(
        const float* __restrict__ h, const float* __restrict__ W,
        const float* __restrict__ b, const float* __restrict__ rs,
        unsigned short* __restrict__ hsb, int n,
        const int* __restrict__ ed, const int* __restrict__ rank,
        const int* __restrict__ off, int* __restrict__ csr_src, int E,
        int nlin) {
    if ((int)blockIdx.x >= nlin) {
        // ---- CSR fill: pos = off[dst] + rank[e], independent stores ----
        int fb = blockIdx.x - nlin;
        int chunk = (E + NFB - 1) / NFB;
        int e1 = min(E, fb * chunk + chunk);
        for (int e = fb * chunk + threadIdx.x; e < e1; e += 256) {
            int d = ed[E + e];
            csr_src[off[d] + rank[e]] = ed[e];
        }
        return;
    }
    // ---- MFMA linear: 128x128 tile, K=128, 4 waves ----
    __shared__ unsigned short sA[128 * 136];  // h tile bf16 (+8 pad)
    __shared__ unsigned short sB[128 * 136];  // W bf16 [n][k]

    const int tid = threadIdx.x;
    const int lane = tid & 63;
    const int wv = tid >> 6;
    const int quad = lane >> 4;
    const int l16 = lane & 15;
    const int row0 = blockIdx.x * 128;

    {
        const float4* h4 = (const float4*)h;
        const float4* W4 = (const float4*)W;
        for (int t = tid; t < 128 * 32; t += 256) {
            int r = t >> 5, c4 = t & 31;
            int row = row0 + r;
            float4 v = make_float4(0.f, 0.f, 0.f, 0.f);
            if (row < n) v = h4[(size_t)row * 32 + c4];
            ushort4 p;
            p.x = f2bf(v.x); p.y = f2bf(v.y); p.z = f2bf(v.z); p.w = f2bf(v.w);
            ((ushort4*)sA)[r * 34 + c4] = p;  // 136/4 = 34
            float4 w = W4[t];
            ushort4 q;
            q.x = f2bf(w.x); q.y = f2bf(w.y); q.z = f2bf(w.z); q.w = f2bf(w.w);
            ((ushort4*)sB)[r * 34 + c4] = q;
        }
    }
    __syncthreads();

    f32x4 acc[2][8];
#pragma unroll
    for (int mt = 0; mt < 2; ++mt)
#pragma unroll
        for (int nt = 0; nt < 8; ++nt) acc[mt][nt] = (f32x4){0.f, 0.f, 0.f, 0.f};

    const int koff = quad * 8;
#pragma unroll
    for (int kc = 0; kc < 4; ++kc) {
        int kbase = kc * 32 + koff;
        bf16x8 a0 = *(const bf16x8*)(sA + (wv * 32 + 0 + l16) * 136 + kbase);
        bf16x8 a1 = *(const bf16x8*)(sA + (wv * 32 + 16 + l16) * 136 + kbase);
#pragma unroll
        for (int nt = 0; nt < 8; ++nt) {
            bf16x8 bb = *(const bf16x8*)(sB + (nt * 16 + l16) * 136 + kbase);
            acc[0][nt] = __builtin_amdgcn_mfma_f32_16x16x32_bf16(a0, bb, acc[0][nt], 0, 0, 0);
            acc[1][nt] = __builtin_amdgcn_mfma_f32_16x16x32_bf16(a1, bb, acc[1][nt], 0, 0, 0);
        }
    }

    // epilogue: bias, scale by rs[row], bf16 store
#pragma unroll
    for (int mt = 0; mt < 2; ++mt) {
#pragma unroll
        for (int r = 0; r < 4; ++r) {
            int row = row0 + wv * 32 + mt * 16 + quad * 4 + r;
            if (row >= n) continue;
            float rsw = rs[row];
#pragma unroll
            for (int nt = 0; nt < 8; ++nt) {
                int col = nt * 16 + l16;
                hsb[(size_t)row * 128 + col] = f2bf((acc[mt][nt][r] + b[col]) * rsw);
            }
        }
    }
}

// Half-wave (32 lanes) per node; lane = 4 channels (ushort4 = 8B).
// out[node] = rs[node] * (hs[node] + sum hs[src]).
#define ACC4(v)               \
    acc.x += bf2f((v).x);     \
    acc.y += bf2f((v).y);     \
    acc.z += bf2f((v).z);     \
    acc.w += bf2f((v).w)
__global__ __launch_bounds__(256) void k_agg(const int* __restrict__ off,
                                             const int* __restrict__ csr_src,
                                             const float* __restrict__ rs,
                                             const unsigned short* __restrict__ hsb,
                                             float* __restrict__ out, int n) {
    int node = blockIdx.x * 8 + (threadIdx.x >> 5);
    if (node >= n) return;
    int lane = threadIdx.x & 31;
    int beg = off[node], end = off[node + 1];
    float rsn = rs[node];

    const ushort4* hp = (const ushort4*)hsb;  // row = 32 ushort4
    ushort4 sv = hp[(size_t)node * 32 + lane];
    float4 acc;
    acc.x = bf2f(sv.x); acc.y = bf2f(sv.y); acc.z = bf2f(sv.z); acc.w = bf2f(sv.w);

    int e = beg;
    while ((e & 3) && e < end) {  // align to int4 boundary
        ushort4 v = hp[(size_t)csr_src[e] * 32 + lane];
        ACC4(v);
        ++e;
    }
    const int4* csr4 = (const int4*)csr_src;
    for (; e + 8 <= end; e += 8) {  // 2 int4 loads + 8 row gathers in flight
        int4 p0 = csr4[(e >> 2) + 0];
        int4 p1 = csr4[(e >> 2) + 1];
        ushort4 v0 = hp[(size_t)p0.x * 32 + lane];
        ushort4 v1 = hp[(size_t)p0.y * 32 + lane];
        ushort4 v2 = hp[(size_t)p0.z * 32 + lane];
        ushort4 v3 = hp[(size_t)p0.w * 32 + lane];
        ushort4 v4 = hp[(size_t)p1.x * 32 + lane];
        ushort4 v5 = hp[(size_t)p1.y * 32 + lane];
        ushort4 v6 = hp[(size_t)p1.z * 32 + lane];
        ushort4 v7 = hp[(size_t)p1.w * 32 + lane];
        ACC4(v0); ACC4(v1); ACC4(v2); ACC4(v3);
        ACC4(v4); ACC4(v5); ACC4(v6); ACC4(v7);
    }
    if (e + 4 <= end) {
        int4 p0 = csr4[e >> 2];
        ushort4 v0 = hp[(size_t)p0.x * 32 + lane];
        ushort4 v1 = hp[(size_t)p0.y * 32 + lane];
        ushort4 v2 = hp[(size_t)p0.z * 32 + lane];
        ushort4 v3 = hp[(size_t)p0.w * 32 + lane];
        ACC4(v0); ACC4(v1); ACC4(v2); ACC4(v3);
        e += 4;
    }
    for (; e < end; ++e) {
        ushort4 v = hp[(size_t)csr_src[e] * 32 + lane];
        ACC4(v);
    }
    acc.x *= rsn; acc.y *= rsn; acc.z *= rsn; acc.w *= rsn;
    ((float4*)out)[(size_t)node * 32 + lane] = acc;
}

extern "C" void kernel_launch(void* const* d_in, const int* in_sizes, int n_in,
                              void* d_out, int out_size, void* d_ws, size_t ws_size,
                              hipStream_t stream) {
    const float* h = (const float*)d_in[0];
    const float* W = (const float*)d_in[1];
    const float* b = (const float*)d_in[2];
    const int* edges = (const int*)d_in[3];

    int n = in_sizes[0] / IN_DIM;   // 50000
    int E = in_sizes[3] / 2;        // 800000
    int nb = (n + 1023) / 1024;     // 49 scan chunks (<=64 required)
    const int nlin = (n + 127) / 128;     // 391 GEMM tiles

    // workspace carve-up (float units, each region 2KB-aligned)
    size_t o = 0;
    auto carve = [&](size_t elems) {
        size_t cur = o;
        o += (elems + 511) & ~(size_t)511;
        return cur;
    };
    float* ws = (float*)d_ws;
    unsigned short* hsb = (unsigned short*)(ws + carve((size_t)n * 64));  // n*128 bf16
    int*   cnt     = (int*)(ws + carve(n));
    int*   off     = (int*)(ws + carve(n + 1));
    int*   rank    = (int*)(ws + carve(E));
    float* rs      = ws + carve(n);
    int*   bsum    = (int*)(ws + carve(64));
    int*   csr_src = (int*)(ws + carve(E));

    float* out = (float*)d_out;

    const int* dstp = edges + E;
    void* bargs[] = {(void*)&dstp, (void*)&cnt, (void*)&rank, (void*)&off,
                     (void*)&bsum, (void*)&rs, (void*)&n, (void*)&E, (void*)&nb};
    hipLaunchCooperativeKernel((void*)k_build, dim3(256), dim3(1024),
                               bargs, 0, stream);
    k_fill_linear<<<nlin + NFB, 256, 0, stream>>>(h, W, b, rs, hsb, n,
                                                  edges, rank, off, csr_src, E, nlin);
    k_agg<<<(n + 7) / 8, 256, 0, stream>>>(off, csr_src, rs, hsb, out, n);
}

// Round 12
// 183.430 us; speedup vs baseline: 1.4398x; 1.4398x over previous
//
#include <hip/hip_runtime.h>

// GCN layer: out = A_norm @ (h @ W^T + b), A_norm = D^-1/2 (A + I) D^-1/2
// Inputs: h [N,128] f32, W [128,128] f32, b [128] f32, edges [2,E] int32
// Output: [N,128] f32
//
// R12: revert to R10 (180.9us). R11's cooperative k_build regressed to
// 264us — grid.sync() on 8-XCD MI355X costs ~25us per barrier (cross-XCD
// drain), far more than the 3 kernel launches it saved. Structure:
//   memset(cnt) -> k_count(+rank) -> k_scan1 -> k_scan3 ->
//   k_fill_linear (MFMA GEMM blocks + atomic-free CSR-fill blocks, fused
//   so scatter latency hides under MFMA) -> k_agg (half-wave/node,
//   ushort4 bf16 gathers, ~L3-gather byte floor).

#define IN_DIM 128
#define OUT_DIM 128

typedef short bf16x8 __attribute__((ext_vector_type(8)));
typedef float f32x4 __attribute__((ext_vector_type(4)));

__device__ __forceinline__ unsigned short f2bf(float f) {
    unsigned u = __float_as_uint(f);
    u += 0x7fffu + ((u >> 16) & 1u);  // round-nearest-even
    return (unsigned short)(u >> 16);
}
__device__ __forceinline__ float bf2f(unsigned short s) {
    return __uint_as_float(((unsigned)s) << 16);
}

// Count degrees AND record each edge's arrival rank within its dst bucket.
__global__ __launch_bounds__(256) void k_count(const int* __restrict__ dst,
                                               int* __restrict__ cnt,
                                               int* __restrict__ rank, int E) {
    int e = blockIdx.x * 256 + threadIdx.x;
    if (e < E) rank[e] = atomicAdd(&cnt[dst[e]], 1);
}

// Pass 1: per-block (1024) exclusive scan of cnt -> off (block-local), block sum -> bsum.
__global__ __launch_bounds__(1024) void k_scan1(const int* __restrict__ cnt,
                                                int* __restrict__ off,
                                                int* __restrict__ bsum, int n) {
    __shared__ int wsum[16];
    const int tid = threadIdx.x;
    const int lane = tid & 63;
    const int wv = tid >> 6;
    int i = blockIdx.x * 1024 + tid;
    int v = (i < n) ? cnt[i] : 0;
    int x = v;
#pragma unroll
    for (int d = 1; d < 64; d <<= 1) {
        int t = __shfl_up(x, d, 64);
        if (lane >= d) x += t;
    }
    if (lane == 63) wsum[wv] = x;
    __syncthreads();
    if (wv == 0) {
        int y = (lane < 16) ? wsum[lane] : 0;
#pragma unroll
        for (int d = 1; d < 16; d <<= 1) {
            int t = __shfl_up(y, d, 64);
            if (lane >= d) y += t;
        }
        if (lane < 16) wsum[lane] = y;
    }
    __syncthreads();
    int waveoff = (wv == 0) ? 0 : wsum[wv - 1];
    if (i < n) off[i] = waveoff + x - v;
    if (tid == 0) bsum[blockIdx.x] = wsum[15];
}

// Pass 2 (fused): each block's wave 0 scans the <=64 block sums to get its
// own base; then all threads add base and emit rs. Block 0 writes off[n].
__global__ __launch_bounds__(1024) void k_scan3(const int* __restrict__ cnt,
                                                const int* __restrict__ bsum,
                                                int* __restrict__ off,
                                                float* __restrict__ rs,
                                                int n, int nb) {
    __shared__ int sbase;
    const int tid = threadIdx.x;
    if (tid < 64) {
        int v = (tid < nb) ? bsum[tid] : 0;
        int x = v;
#pragma unroll
        for (int d = 1; d < 64; d <<= 1) {
            int t = __shfl_up(x, d, 64);
            if (tid >= d) x += t;
        }
        if (tid == (int)blockIdx.x) sbase = x - v;         // exclusive base
        if (blockIdx.x == 0 && tid == nb - 1) off[n] = x;  // grand total
    }
    __syncthreads();
    int i = blockIdx.x * 1024 + tid;
    if (i >= n) return;
    off[i] = off[i] + sbase;
    rs[i] = rsqrtf((float)(cnt[i] + 1));
}

// Fused: blocks [0,nlin) compute hs = (h@W^T+b)*rs via MFMA;
// blocks [nlin, nlin+NFB) do the atomic-free CSR fill (grid-stride chunks).
// Fill's scattered stores overlap the GEMM instead of serializing after it.
#define NFB 1024
__global__ __launch_bounds__(256) void k_fill_linear(
        const float* __restrict__ h, const float* __restrict__ W,
        const float* __restrict__ b, const float* __restrict__ rs,
        unsigned short* __restrict__ hsb, int n,
        const int* __restrict__ ed, const int* __restrict__ rank,
        const int* __restrict__ off, int* __restrict__ csr_src, int E,
        int nlin) {
    if ((int)blockIdx.x >= nlin) {
        // ---- CSR fill: pos = off[dst] + rank[e], independent stores ----
        int fb = blockIdx.x - nlin;
        int chunk = (E + NFB - 1) / NFB;
        int e1 = min(E, fb * chunk + chunk);
        for (int e = fb * chunk + threadIdx.x; e < e1; e += 256) {
            int d = ed[E + e];
            csr_src[off[d] + rank[e]] = ed[e];
        }
        return;
    }
    // ---- MFMA linear: 128x128 tile, K=128, 4 waves ----
    __shared__ unsigned short sA[128 * 136];  // h tile bf16 (+8 pad)
    __shared__ unsigned short sB[128 * 136];  // W bf16 [n][k]

    const int tid = threadIdx.x;
    const int lane = tid & 63;
    const int wv = tid >> 6;
    const int quad = lane >> 4;
    const int l16 = lane & 15;
    const int row0 = blockIdx.x * 128;

    {
        const float4* h4 = (const float4*)h;
        const float4* W4 = (const float4*)W;
        for (int t = tid; t < 128 * 32; t += 256) {
            int r = t >> 5, c4 = t & 31;
            int row = row0 + r;
            float4 v = make_float4(0.f, 0.f, 0.f, 0.f);
            if (row < n) v = h4[(size_t)row * 32 + c4];
            ushort4 p;
            p.x = f2bf(v.x); p.y = f2bf(v.y); p.z = f2bf(v.z); p.w = f2bf(v.w);
            ((ushort4*)sA)[r * 34 + c4] = p;  // 136/4 = 34
            float4 w = W4[t];
            ushort4 q;
            q.x = f2bf(w.x); q.y = f2bf(w.y); q.z = f2bf(w.z); q.w = f2bf(w.w);
            ((ushort4*)sB)[r * 34 + c4] = q;
        }
    }
    __syncthreads();

    f32x4 acc[2][8];
#pragma unroll
    for (int mt = 0; mt < 2; ++mt)
#pragma unroll
        for (int nt = 0; nt < 8; ++nt) acc[mt][nt] = (f32x4){0.f, 0.f, 0.f, 0.f};

    const int koff = quad * 8;
#pragma unroll
    for (int kc = 0; kc < 4; ++kc) {
        int kbase = kc * 32 + koff;
        bf16x8 a0 = *(const bf16x8*)(sA + (wv * 32 + 0 + l16) * 136 + kbase);
        bf16x8 a1 = *(const bf16x8*)(sA + (wv * 32 + 16 + l16) * 136 + kbase);
#pragma unroll
        for (int nt = 0; nt < 8; ++nt) {
            bf16x8 bb = *(const bf16x8*)(sB + (nt * 16 + l16) * 136 + kbase);
            acc[0][nt] = __builtin_amdgcn_mfma_f32_16x16x32_bf16(a0, bb, acc[0][nt], 0, 0, 0);
            acc[1][nt] = __builtin_amdgcn_mfma_f32_16x16x32_bf16(a1, bb, acc[1][nt], 0, 0, 0);
        }
    }

    // epilogue: bias, scale by rs[row], bf16 store
#pragma unroll
    for (int mt = 0; mt < 2; ++mt) {
#pragma unroll
        for (int r = 0; r < 4; ++r) {
            int row = row0 + wv * 32 + mt * 16 + quad * 4 + r;
            if (row >= n) continue;
            float rsw = rs[row];
#pragma unroll
            for (int nt = 0; nt < 8; ++nt) {
                int col = nt * 16 + l16;
                hsb[(size_t)row * 128 + col] = f2bf((acc[mt][nt][r] + b[col]) * rsw);
            }
        }
    }
}

// Half-wave (32 lanes) per node; lane = 4 channels (ushort4 = 8B).
// One gather instruction serves 2 edges; int4 index load serves 8.
// out[node] = rs[node] * (hs[node] + sum hs[src]).
#define ACC4(v)               \
    acc.x += bf2f((v).x);     \
    acc.y += bf2f((v).y);     \
    acc.z += bf2f((v).z);     \
    acc.w += bf2f((v).w)
__global__ __launch_bounds__(256) void k_agg(const int* __restrict__ off,
                                             const int* __restrict__ csr_src,
                                             const float* __restrict__ rs,
                                             const unsigned short* __restrict__ hsb,
                                             float* __restrict__ out, int n) {
    int node = blockIdx.x * 8 + (threadIdx.x >> 5);
    if (node >= n) return;
    int lane = threadIdx.x & 31;
    int beg = off[node], end = off[node + 1];
    float rsn = rs[node];

    const ushort4* hp = (const ushort4*)hsb;  // row = 32 ushort4
    ushort4 sv = hp[(size_t)node * 32 + lane];
    float4 acc;
    acc.x = bf2f(sv.x); acc.y = bf2f(sv.y); acc.z = bf2f(sv.z); acc.w = bf2f(sv.w);

    int e = beg;
    while ((e & 3) && e < end) {  // align to int4 boundary
        ushort4 v = hp[(size_t)csr_src[e] * 32 + lane];
        ACC4(v);
        ++e;
    }
    const int4* csr4 = (const int4*)csr_src;
    for (; e + 8 <= end; e += 8) {  // 2 int4 loads + 8 row gathers in flight
        int4 p0 = csr4[(e >> 2) + 0];
        int4 p1 = csr4[(e >> 2) + 1];
        ushort4 v0 = hp[(size_t)p0.x * 32 + lane];
        ushort4 v1 = hp[(size_t)p0.y * 32 + lane];
        ushort4 v2 = hp[(size_t)p0.z * 32 + lane];
        ushort4 v3 = hp[(size_t)p0.w * 32 + lane];
        ushort4 v4 = hp[(size_t)p1.x * 32 + lane];
        ushort4 v5 = hp[(size_t)p1.y * 32 + lane];
        ushort4 v6 = hp[(size_t)p1.z * 32 + lane];
        ushort4 v7 = hp[(size_t)p1.w * 32 + lane];
        ACC4(v0); ACC4(v1); ACC4(v2); ACC4(v3);
        ACC4(v4); ACC4(v5); ACC4(v6); ACC4(v7);
    }
    if (e + 4 <= end) {
        int4 p0 = csr4[e >> 2];
        ushort4 v0 = hp[(size_t)p0.x * 32 + lane];
        ushort4 v1 = hp[(size_t)p0.y * 32 + lane];
        ushort4 v2 = hp[(size_t)p0.z * 32 + lane];
        ushort4 v3 = hp[(size_t)p0.w * 32 + lane];
        ACC4(v0); ACC4(v1); ACC4(v2); ACC4(v3);
        e += 4;
    }
    for (; e < end; ++e) {
        ushort4 v = hp[(size_t)csr_src[e] * 32 + lane];
        ACC4(v);
    }
    acc.x *= rsn; acc.y *= rsn; acc.z *= rsn; acc.w *= rsn;
    ((float4*)out)[(size_t)node * 32 + lane] = acc;
}

extern "C" void kernel_launch(void* const* d_in, const int* in_sizes, int n_in,
                              void* d_out, int out_size, void* d_ws, size_t ws_size,
                              hipStream_t stream) {
    const float* h = (const float*)d_in[0];
    const float* W = (const float*)d_in[1];
    const float* b = (const float*)d_in[2];
    const int* edges = (const int*)d_in[3];

    const int n = in_sizes[0] / IN_DIM;   // 50000
    const int E = in_sizes[3] / 2;        // 800000
    const int nb = (n + 1023) / 1024;     // 49 scan blocks (<=64 required)
    const int nlin = (n + 127) / 128;     // 391 GEMM tiles

    // workspace carve-up (float units, each region 2KB-aligned)
    size_t o = 0;
    auto carve = [&](size_t elems) {
        size_t cur = o;
        o += (elems + 511) & ~(size_t)511;
        return cur;
    };
    float* ws = (float*)d_ws;
    unsigned short* hsb = (unsigned short*)(ws + carve((size_t)n * 64));  // n*128 bf16
    int*   cnt     = (int*)(ws + carve(n));
    int*   off     = (int*)(ws + carve(n + 1));
    int*   rank    = (int*)(ws + carve(E));
    float* rs      = ws + carve(n);
    int*   bsum    = (int*)(ws + carve(64));
    int*   csr_src = (int*)(ws + carve(E));

    float* out = (float*)d_out;

    hipMemsetAsync(cnt, 0, (size_t)n * sizeof(int), stream);
    k_count<<<(E + 255) / 256, 256, 0, stream>>>(edges + E, cnt, rank, E);
    k_scan1<<<nb, 1024, 0, stream>>>(cnt, off, bsum, n);
    k_scan3<<<nb, 1024, 0, stream>>>(cnt, bsum, off, rs, n, nb);
    k_fill_linear<<<nlin + NFB, 256, 0, stream>>>(h, W, b, rs, hsb, n,
                                                  edges, rank, off, csr_src, E, nlin);
    k_agg<<<(n + 7) / 8, 256, 0, stream>>>(off, csr_src, rs, hsb, out, n);
}